// Round 9
// baseline (633.367 us; speedup 1.0000x reference)
//
#include <hip/hip_runtime.h>
#include <cstdio>

// ---------------------------------------------------------------------------
// GraphMessagePassing. Round-9: dst-sorted segmented aggregation + R8 MFMA.
//  Diagnosis: R6/R7/R8 all converge to ~330-390us = 480MB of random-granule
//  HBM traffic (312MB of it atomic write-through) at ~1.4TB/s. Fix:
//  - CSR-style sort by dst (hist -> 3-pass scan -> place): edges with equal
//    dst become contiguous; place also emits sorted_src/dst/eid so edge-kernel
//    index reads stay coalesced.
//  - edge kernel = R8 MFMA f16-split compute (pipes nearly free) + segmented
//    scan epilogue: messages(+b2) -> LDS tile, 16-step uniform scan, ONE
//    256B atomic per dst-run (~1.6/wave) instead of 16 -> atomic HBM traffic
//    320MB -> ~40MB.
//  Node kernel: unchanged R7 (known-good).
// ---------------------------------------------------------------------------

typedef _Float16 f16;
typedef f16  f16x8 __attribute__((ext_vector_type(8)));
typedef f16  f16x4 __attribute__((ext_vector_type(4)));
typedef float f32x4 __attribute__((ext_vector_type(4)));

#define MFMA16(a, b, c) __builtin_amdgcn_mfma_f32_16x16x32_f16(a, b, c, 0, 0, 0)

// ---- pre-kernel: split node features into f16 hi/lo planes ---------------
__global__ void conv_features(const float* __restrict__ x,
                              f16* __restrict__ xh, f16* __restrict__ xl,
                              int n4) {
    int i = blockIdx.x * blockDim.x + threadIdx.x;
    if (i >= n4) return;
    float4 v = ((const float4*)x)[i];
    float vv[4] = {v.x, v.y, v.z, v.w};
    f16x4 hi, lo;
    #pragma unroll
    for (int j = 0; j < 4; ++j) {
        f16 h = (f16)vv[j];
        hi[j] = h;
        lo[j] = (f16)(vv[j] - (float)h);
    }
    ((f16x4*)xh)[i] = hi;
    ((f16x4*)xl)[i] = lo;
}

// ---- pre-kernel: transpose + split weights: W1^T[64][96] (k-pad), W2^T[64][64]
__global__ void conv_weights(const float* __restrict__ w1,
                             const float* __restrict__ w2,
                             f16* __restrict__ w1th, f16* __restrict__ w1tl,
                             f16* __restrict__ w2th, f16* __restrict__ w2tl) {
    int idx = blockIdx.x * blockDim.x + threadIdx.x;
    if (idx < 64 * 96) {
        int c = idx / 96, k = idx % 96;
        float v = (k < 80) ? w1[k * 64 + c] : 0.f;
        f16 h = (f16)v;
        w1th[c * 96 + k] = h;
        w1tl[c * 96 + k] = (f16)(v - (float)h);
    } else if (idx < 64 * 96 + 64 * 64) {
        int t = idx - 64 * 96;
        int c = t / 64, k = t % 64;
        float v = w2[k * 64 + c];
        f16 h = (f16)v;
        w2th[c * 64 + k] = h;
        w2tl[c * 64 + k] = (f16)(v - (float)h);
    }
}

// ---- sort passes -----------------------------------------------------------
__global__ void hist_k(const int* __restrict__ dst, int* __restrict__ cnt,
                       int E, int N) {
    for (int e = blockIdx.x * blockDim.x + threadIdx.x; e < E;
         e += gridDim.x * blockDim.x) {
        int d = dst[e];
        if ((unsigned)d >= (unsigned)N) d = 0;
        atomicAdd(&cnt[d], 1);
    }
}

__global__ void scan_part(const int* __restrict__ cnt, int* __restrict__ part,
                          int N) {
    __shared__ int sh[256];
    const int b = blockIdx.x, t = threadIdx.x;
    const int end = min((b + 1) * 1024, N);
    int s = 0;
    for (int i = b * 1024 + t; i < end; i += 256) s += cnt[i];
    sh[t] = s;
    __syncthreads();
    for (int st = 128; st > 0; st >>= 1) {
        if (t < st) sh[t] += sh[t + st];
        __syncthreads();
    }
    if (t == 0) part[b] = sh[0];
}

__global__ void scan_top(int* part, int nb) {
    if (blockIdx.x == 0 && threadIdx.x == 0) {
        int run = 0;
        for (int i = 0; i < nb; ++i) { int v = part[i]; part[i] = run; run += v; }
    }
}

__global__ void scan_fin(const int* __restrict__ cnt, const int* __restrict__ part,
                         int* __restrict__ offs, int N) {
    __shared__ int sh[256];
    const int b = blockIdx.x, t = threadIdx.x;
    const int i0 = b * 1024 + t * 4;
    int v[4]; int s = 0;
    #pragma unroll
    for (int j = 0; j < 4; ++j) {
        int idx = i0 + j;
        v[j] = (idx < N) ? cnt[idx] : 0;
        s += v[j];
    }
    sh[t] = s;
    __syncthreads();
    for (int st = 1; st < 256; st <<= 1) {
        int a = (t >= st) ? sh[t - st] : 0;
        __syncthreads();
        sh[t] += a;
        __syncthreads();
    }
    int run = sh[t] - s + part[b];      // exclusive prefix for this chunk
    #pragma unroll
    for (int j = 0; j < 4; ++j) {
        int idx = i0 + j;
        if (idx < N) offs[idx] = run;
        run += v[j];
    }
}

__global__ void place_k(const int* __restrict__ eidx, int* __restrict__ offs,
                        int* __restrict__ ssrc, int* __restrict__ sdst,
                        int* __restrict__ seid, int E, int N) {
    int e = blockIdx.x * blockDim.x + threadIdx.x;
    if (e >= E) return;
    int d = eidx[(size_t)E + e]; if ((unsigned)d >= (unsigned)N) d = 0;
    int s = eidx[e];             if ((unsigned)s >= (unsigned)N) s = 0;
    int p = atomicAdd(&offs[d], 1);     // p < E by construction
    ssrc[p] = s; sdst[p] = d; seid[p] = e;
}

// ---- edge kernel: MFMA f16-split + segmented-scan epilogue ------------------
__global__ __launch_bounds__(256)
void GraphMessagePassing_5952824672257_kernel(
    const f16* __restrict__ nh, const f16* __restrict__ nl,   // [N,64] hi/lo
    const float* __restrict__ edgef,                          // [E,16] f32
    const int* __restrict__ ssrc, const int* __restrict__ sdst,
    const int* __restrict__ seid,
    const f16* __restrict__ w1th, const f16* __restrict__ w1tl, // [64][96]
    const f16* __restrict__ w2th, const f16* __restrict__ w2tl, // [64][64]
    const float* __restrict__ b1, const float* __restrict__ b2,
    float* __restrict__ agg, int n_edges, int n_nodes)
{
    // Hhi/Hlo live through GEMM2; F (message tile) aliases them afterwards.
    __shared__ __align__(16) char smem[18432];
    f16*   Hhi = (f16*)smem;             // [64][72]
    f16*   Hlo = (f16*)(smem + 9216);    // [64][72]
    float* F   = (float*)smem;           // [64][68] (17408 B <= 18432)

    const int lane = threadIdx.x & 63;
    const int wid  = threadIdx.x >> 6;
    const int r16  = lane & 15;
    const int g    = lane >> 4;
    const long base = (long)blockIdx.x * 64 + wid * 16;

    long es = base + r16;
    if (es >= n_edges) es = n_edges - 1;
    const int s   = ssrc[es];            // coalesced (sorted arrays)
    const int eid = seid[es];

    // ---- GEMM1: C1[16e][64ch] = X[16e][96k] @ W1[96k][64ch]
    f32x4 acc[4] = {{0.f,0.f,0.f,0.f},{0.f,0.f,0.f,0.f},
                    {0.f,0.f,0.f,0.f},{0.f,0.f,0.f,0.f}};
    #pragma unroll
    for (int kt = 0; kt < 2; ++kt) {
        const int k0 = kt * 32 + g * 8;
        f16x8 ahi = *(const f16x8*)&nh[(size_t)s * 64 + k0];
        f16x8 alo = *(const f16x8*)&nl[(size_t)s * 64 + k0];
        #pragma unroll
        for (int nt = 0; nt < 4; ++nt) {
            const int c = nt * 16 + r16;
            f16x8 bhi = *(const f16x8*)&w1th[c * 96 + k0];
            f16x8 blo = *(const f16x8*)&w1tl[c * 96 + k0];
            acc[nt] = MFMA16(ahi, bhi, acc[nt]);
            acc[nt] = MFMA16(ahi, blo, acc[nt]);
            acc[nt] = MFMA16(alo, bhi, acc[nt]);
        }
    }
    {   // k 64..95: g<2 from edgef (gathered via seid), g>=2 zero-pad
        f16x8 ahi = {}; f16x8 alo = {};
        if (g < 2) {
            const float* ep = edgef + (size_t)eid * 16 + g * 8;
            float4 v0 = *(const float4*)(ep);
            float4 v1 = *(const float4*)(ep + 4);
            float xv[8] = {v0.x, v0.y, v0.z, v0.w, v1.x, v1.y, v1.z, v1.w};
            #pragma unroll
            for (int j = 0; j < 8; ++j) {
                f16 h = (f16)xv[j];
                ahi[j] = h;
                alo[j] = (f16)(xv[j] - (float)h);
            }
        }
        const int k0 = 64 + g * 8;
        #pragma unroll
        for (int nt = 0; nt < 4; ++nt) {
            const int c = nt * 16 + r16;
            f16x8 bhi = *(const f16x8*)&w1th[c * 96 + k0];
            f16x8 blo = *(const f16x8*)&w1tl[c * 96 + k0];
            acc[nt] = MFMA16(ahi, bhi, acc[nt]);
            acc[nt] = MFMA16(ahi, blo, acc[nt]);
            acc[nt] = MFMA16(alo, bhi, acc[nt]);
        }
    }

    // ---- +b1, relu, f16-split -> H tile (wave-private rows)
    const int ebase = wid * 16 + g * 4;
    #pragma unroll
    for (int nt = 0; nt < 4; ++nt) {
        const int ch = nt * 16 + r16;
        const float bv = b1[ch];
        #pragma unroll
        for (int reg = 0; reg < 4; ++reg) {
            float h = fmaxf(acc[nt][reg] + bv, 0.f);
            f16 hh = (f16)h;
            Hhi[(ebase + reg) * 72 + ch] = hh;
            Hlo[(ebase + reg) * 72 + ch] = (f16)(h - (float)hh);
        }
    }
    __syncthreads();

    // ---- GEMM2: C2[16e][64ch] = H[16e][64k] @ W2[64k][64ch]
    f32x4 acc2[4] = {{0.f,0.f,0.f,0.f},{0.f,0.f,0.f,0.f},
                     {0.f,0.f,0.f,0.f},{0.f,0.f,0.f,0.f}};
    const int arow = wid * 16 + r16;
    #pragma unroll
    for (int kt = 0; kt < 2; ++kt) {
        const int k0 = kt * 32 + g * 8;
        f16x8 ahi = *(const f16x8*)&Hhi[arow * 72 + k0];
        f16x8 alo = *(const f16x8*)&Hlo[arow * 72 + k0];
        #pragma unroll
        for (int nt = 0; nt < 4; ++nt) {
            const int c = nt * 16 + r16;
            f16x8 bhi = *(const f16x8*)&w2th[c * 64 + k0];
            f16x8 blo = *(const f16x8*)&w2tl[c * 64 + k0];
            acc2[nt] = MFMA16(ahi, bhi, acc2[nt]);
            acc2[nt] = MFMA16(ahi, blo, acc2[nt]);
            acc2[nt] = MFMA16(alo, bhi, acc2[nt]);
        }
    }
    __syncthreads();   // all H reads done before F aliases the same bytes

    // ---- messages(+b2) -> F[edge][ch] (wave-private rows, no barrier needed)
    #pragma unroll
    for (int nt = 0; nt < 4; ++nt) {
        const int ch = nt * 16 + r16;
        const float bv = b2[ch];
        #pragma unroll
        for (int reg = 0; reg < 4; ++reg)
            F[(ebase + reg) * 68 + ch] = acc2[nt][reg] + bv;
    }

    // ---- segmented scan over the wave's 16 sorted edges; lane = channel
    const int c = lane;
    long e0c = (base < n_edges) ? base : (long)n_edges - 1;
    int curd = sdst[e0c];                      // wave-uniform
    float accv = 0.f;
    #pragma unroll 1
    for (int i = 0; i < 16; ++i) {
        const long ee = base + i;
        const bool v = ee < n_edges;
        const int dnew = v ? sdst[ee] : curd;  // wave-uniform
        if (dnew != curd) {                    // uniform branch
            atomicAdd(agg + (size_t)curd * 64 + c, accv);
            accv = 0.f; curd = dnew;
        }
        if (v) accv += F[(wid * 16 + i) * 68 + c];
    }
    atomicAdd(agg + (size_t)curd * 64 + c, accv);
}

// ---- node phase: unchanged from R7 (known-good) -----------------------------
#define TPB 256

__global__ __launch_bounds__(TPB)
void node_mlp_coop(
    const float* __restrict__ nodef, const float* __restrict__ agg,
    const float* __restrict__ w1, const float* __restrict__ b1,
    const float* __restrict__ w2, const float* __restrict__ b2,
    float* __restrict__ out, int n_nodes)
{
    __shared__ float HB[64][65];
    float* __restrict__ Xf = &HB[0][0];

    const int tid  = threadIdx.x;
    const int lane = tid & 63;
    const int wch  = __builtin_amdgcn_readfirstlane(tid >> 6) * 16;
    const long base = (long)blockIdx.x * 64;

    const int r  = tid & 15;
    const int e0 = tid >> 4;
    size_t rows[4];
    #pragma unroll
    for (int i = 0; i < 4; ++i) {
        long row = base + e0 + i * 16;
        if (row >= n_nodes) row = n_nodes - 1;
        if (row < 0) row = 0;
        rows[i] = (size_t)row * 64;
    }

    float h[16];
    #pragma unroll
    for (int c = 0; c < 16; ++c) h[c] = b1[wch + c];

    float pf[4];
    #pragma unroll
    for (int i = 0; i < 4; ++i) pf[i] = nodef[rows[i] + r];
    #pragma unroll
    for (int i = 0; i < 4; ++i) Xf[r * 66 + e0 + i * 16] = pf[i];
    #pragma unroll
    for (int i = 0; i < 4; ++i) pf[i] = nodef[rows[i] + 16 + r];
    __syncthreads();

    #pragma unroll
    for (int kc = 0; kc < 8; ++kc) {
        const int cur = kc & 1;
        #pragma unroll 4
        for (int r2 = 0; r2 < 16; ++r2) {
            const float xk = Xf[cur * 1056 + r2 * 66 + lane];
            const float* __restrict__ wr = w1 + (kc * 16 + r2) * 64 + wch;
            #pragma unroll
            for (int c = 0; c < 16; ++c) h[c] = fmaf(xk, wr[c], h[c]);
        }
        if (kc < 7) {
            #pragma unroll
            for (int i = 0; i < 4; ++i)
                Xf[(cur ^ 1) * 1056 + r * 66 + e0 + i * 16] = pf[i];
            if (kc < 6) {
                const float* __restrict__ src = (kc + 2 < 4) ? nodef : agg;
                const int ko = ((kc + 2) & 3) * 16;
                #pragma unroll
                for (int i = 0; i < 4; ++i) pf[i] = src[rows[i] + ko + r];
            }
            __syncthreads();
        }
    }
    __syncthreads();

    #pragma unroll
    for (int c = 0; c < 16; ++c) HB[lane][wch + c] = fmaxf(h[c], 0.f);
    __syncthreads();

    float m[16];
    #pragma unroll
    for (int c = 0; c < 16; ++c) m[c] = b2[wch + c];
    #pragma unroll 4
    for (int t = 0; t < 64; ++t) {
        const float xt = HB[lane][t];
        const float* __restrict__ wr = w2 + t * 64 + wch;
        #pragma unroll
        for (int c = 0; c < 16; ++c) m[c] = fmaf(xt, wr[c], m[c]);
    }
    __syncthreads();

    #pragma unroll
    for (int c = 0; c < 16; ++c) HB[lane][wch + c] = m[c];
    __syncthreads();

    const int oc  = lane & 15;
    const int er4 = lane >> 4;
    #pragma unroll
    for (int g = 0; g < 16; ++g) {
        const int le = g * 4 + er4;
        const float v = HB[le][wch + oc];
        if (base + le < n_nodes)
            out[(size_t)(base + le) * 64 + wch + oc] = v;
    }
}

extern "C" void kernel_launch(void* const* d_in, const int* in_sizes, int n_in,
                              void* d_out, int out_size, void* d_ws, size_t ws_size,
                              hipStream_t stream) {
    const float* nodef = (const float*)d_in[0];
    const float* edgef = (const float*)d_in[1];
    const int*   eidx  = (const int*)d_in[2];
    const float* w_m1  = (const float*)d_in[3];
    const float* b_m1  = (const float*)d_in[4];
    const float* w_m2  = (const float*)d_in[5];
    const float* b_m2  = (const float*)d_in[6];
    const float* w_u1  = (const float*)d_in[7];
    const float* b_u1  = (const float*)d_in[8];
    const float* w_u2  = (const float*)d_in[9];
    const float* b_u2  = (const float*)d_in[10];
    float* out = (float*)d_out;

    const int n_nodes = out_size / 64;
    const int n_edges = in_sizes[2] / 2;
    if (n_edges <= 0 || n_nodes <= 0) return;

    // workspace layout
    char* wsb = (char*)d_ws;
    size_t o = 0;
    float* agg = (float*)wsb;           o += ((size_t)n_nodes * 64 * 4 + 255) & ~(size_t)255;
    f16* nh   = (f16*)(wsb + o);        o += (size_t)n_nodes * 64 * 2;
    f16* nl   = (f16*)(wsb + o);        o += (size_t)n_nodes * 64 * 2;
    f16* w1th = (f16*)(wsb + o);        o += 64 * 96 * 2;
    f16* w1tl = (f16*)(wsb + o);        o += 64 * 96 * 2;
    f16* w2th = (f16*)(wsb + o);        o += 64 * 64 * 2;
    f16* w2tl = (f16*)(wsb + o);        o += 64 * 64 * 2;
    o = (o + 255) & ~(size_t)255;
    int* cnt  = (int*)(wsb + o);        o += (size_t)n_nodes * 4;
    int* offs = (int*)(wsb + o);        o += (size_t)n_nodes * 4;
    int* part = (int*)(wsb + o);        o += 4096;
    int* ssrc = (int*)(wsb + o);        o += (size_t)n_edges * 4;
    int* sdst = (int*)(wsb + o);        o += (size_t)n_edges * 4;
    int* seid = (int*)(wsb + o);        o += (size_t)n_edges * 4;

    fprintf(stderr, "[KL] mfma+sorted-seg E=%d N=%d ws=%zu used=%zu\n",
            n_edges, n_nodes, ws_size, o);
    fflush(stderr);

    hipMemsetAsync(agg, 0, (size_t)n_nodes * 64 * sizeof(float), stream);
    hipMemsetAsync(cnt, 0, (size_t)n_nodes * sizeof(int), stream);

    // feature/weight conversion
    const int n4 = n_nodes * 64 / 4;
    conv_features<<<(n4 + 255) / 256, 256, 0, stream>>>(nodef, nh, nl, n4);
    conv_weights<<<(64 * 96 + 64 * 64 + 255) / 256, 256, 0, stream>>>(
        w_m1, w_m2, w1th, w1tl, w2th, w2tl);

    // dst-sort (counting sort)
    const int nb = (n_nodes + 1023) / 1024;
    hist_k<<<1024, 256, 0, stream>>>(eidx + n_edges, cnt, n_edges, n_nodes);
    scan_part<<<nb, 256, 0, stream>>>(cnt, part, n_nodes);
    scan_top<<<1, 64, 0, stream>>>(part, nb);
    scan_fin<<<nb, 256, 0, stream>>>(cnt, part, offs, n_nodes);
    place_k<<<(n_edges + 255) / 256, 256, 0, stream>>>(
        eidx, offs, ssrc, sdst, seid, n_edges, n_nodes);

    // edge phase
    const int blocks_e = (n_edges + 63) / 64;
    GraphMessagePassing_5952824672257_kernel<<<blocks_e, 256, 0, stream>>>(
        nh, nl, edgef, ssrc, sdst, seid, w1th, w1tl, w2th, w2tl,
        b_m1, b_m2, agg, n_edges, n_nodes);

    // node phase
    const int blocks_n = (n_nodes + 63) / 64;
    node_mlp_coop<<<blocks_n, TPB, 0, stream>>>(
        nodef, agg, w_u1, b_u1, w_u2, b_u2, out, n_nodes);

    hipError_t le = hipGetLastError();
    fprintf(stderr, "[KL] last=%d(%s)\n", (int)le, hipGetErrorName(le));
    fflush(stderr);
}

// Round 10
// 485.748 us; speedup vs baseline: 1.3039x; 1.3039x over previous
//
#include <hip/hip_runtime.h>
#include <cstdio>

// ---------------------------------------------------------------------------
// GraphMessagePassing. Round-10: fragment-major weights (coalesced B-loads).
//  Diagnosis R8/R9: per-lane weight-fragment loads are address-divergent
//  (16-64 distinct lines/instr); TA line throughput ~1/cy makes them the
//  wall (~3000cy/wave) while MFMA/VALU/HBM all idle. Fix: pre-pack every
//  MFMA B-fragment contiguously (frag-major: [frag][lane][8] f16) so each
//  B-load is one coalesced 1KB access. Also:
//  - segmented-scan dsts: 1 coalesced load + __shfl (was 17 serial loads)
//  - node kernel ported to same MFMA structure (no gathers, plain stores)
//  Sort pipeline (dst counting-sort) and conv_features kept from R9.
// ---------------------------------------------------------------------------

typedef _Float16 f16;
typedef f16  f16x8 __attribute__((ext_vector_type(8)));
typedef f16  f16x4 __attribute__((ext_vector_type(4)));
typedef float f32x4 __attribute__((ext_vector_type(4)));

#define MFMA16(a, b, c) __builtin_amdgcn_mfma_f32_16x16x32_f16(a, b, c, 0, 0, 0)

// ---- pre-kernel: split node features into f16 hi/lo planes -----------------
__global__ void conv_features(const float* __restrict__ x,
                              f16* __restrict__ xh, f16* __restrict__ xl,
                              int n4) {
    int i = blockIdx.x * blockDim.x + threadIdx.x;
    if (i >= n4) return;
    float4 v = ((const float4*)x)[i];
    float vv[4] = {v.x, v.y, v.z, v.w};
    f16x4 hi, lo;
    #pragma unroll
    for (int j = 0; j < 4; ++j) {
        f16 h = (f16)vv[j];
        hi[j] = h;
        lo[j] = (f16)(vv[j] - (float)h);
    }
    ((f16x4*)xh)[i] = hi;
    ((f16x4*)xl)[i] = lo;
}

// ---- pre-kernel: fragment-major weight packing ------------------------------
// B-frag layout (16x16x32 MFMA): lane l -> col c = nt*16 + (l&15),
//                                k = kt*32 + (l>>4)*8 + j.
// Tables (f16): W1F hi[0,6144) lo[6144,12288)   (kt=0..2, K=96 zero-pad>=80)
//              W2F hi[0,4096) lo[4096,8192)     (kt=0..1)
//              U1F hi[0,8192) lo[8192,16384)    (kt=0..3, K=128)
//              U2F hi[0,4096) lo[4096,8192)     (kt=0..1)
__global__ void conv_wfrag(const float* __restrict__ w1,
                           const float* __restrict__ w2,
                           const float* __restrict__ wu1,
                           const float* __restrict__ wu2,
                           f16* __restrict__ W1F, f16* __restrict__ W2F,
                           f16* __restrict__ U1F, f16* __restrict__ U2F) {
    int idx = blockIdx.x * blockDim.x + threadIdx.x;
    if (idx >= 22528) return;
    f16* dh; f16* dl; float v;
    if (idx < 6144) {
        int kt = idx / 2048, rem = idx % 2048;
        int nt = rem / 512, r = rem % 512, l = r >> 3, j = r & 7;
        int c = nt * 16 + (l & 15), k = kt * 32 + (l >> 4) * 8 + j;
        v = (k < 80) ? w1[k * 64 + c] : 0.f;
        dh = &W1F[idx]; dl = &W1F[6144 + idx];
    } else if (idx < 6144 + 4096) {
        int t = idx - 6144;
        int kt = t / 2048, rem = t % 2048;
        int nt = rem / 512, r = rem % 512, l = r >> 3, j = r & 7;
        int c = nt * 16 + (l & 15), k = kt * 32 + (l >> 4) * 8 + j;
        v = w2[k * 64 + c];
        dh = &W2F[t]; dl = &W2F[4096 + t];
    } else if (idx < 6144 + 4096 + 8192) {
        int t = idx - 6144 - 4096;
        int kt = t / 2048, rem = t % 2048;
        int nt = rem / 512, r = rem % 512, l = r >> 3, j = r & 7;
        int c = nt * 16 + (l & 15), k = kt * 32 + (l >> 4) * 8 + j;
        v = wu1[k * 64 + c];
        dh = &U1F[t]; dl = &U1F[8192 + t];
    } else {
        int t = idx - 6144 - 4096 - 8192;
        int kt = t / 2048, rem = t % 2048;
        int nt = rem / 512, r = rem % 512, l = r >> 3, j = r & 7;
        int c = nt * 16 + (l & 15), k = kt * 32 + (l >> 4) * 8 + j;
        v = wu2[k * 64 + c];
        dh = &U2F[t]; dl = &U2F[4096 + t];
    }
    f16 h = (f16)v;
    *dh = h;
    *dl = (f16)(v - (float)h);
}

// ---- sort passes (unchanged from R9) ----------------------------------------
__global__ void hist_k(const int* __restrict__ dst, int* __restrict__ cnt,
                       int E, int N) {
    for (int e = blockIdx.x * blockDim.x + threadIdx.x; e < E;
         e += gridDim.x * blockDim.x) {
        int d = dst[e];
        if ((unsigned)d >= (unsigned)N) d = 0;
        atomicAdd(&cnt[d], 1);
    }
}

__global__ void scan_part(const int* __restrict__ cnt, int* __restrict__ part,
                          int N) {
    __shared__ int sh[256];
    const int b = blockIdx.x, t = threadIdx.x;
    const int end = min((b + 1) * 1024, N);
    int s = 0;
    for (int i = b * 1024 + t; i < end; i += 256) s += cnt[i];
    sh[t] = s;
    __syncthreads();
    for (int st = 128; st > 0; st >>= 1) {
        if (t < st) sh[t] += sh[t + st];
        __syncthreads();
    }
    if (t == 0) part[b] = sh[0];
}

__global__ void scan_top(int* part, int nb) {
    if (blockIdx.x == 0 && threadIdx.x == 0) {
        int run = 0;
        for (int i = 0; i < nb; ++i) { int v = part[i]; part[i] = run; run += v; }
    }
}

__global__ void scan_fin(const int* __restrict__ cnt, const int* __restrict__ part,
                         int* __restrict__ offs, int N) {
    __shared__ int sh[256];
    const int b = blockIdx.x, t = threadIdx.x;
    const int i0 = b * 1024 + t * 4;
    int v[4]; int s = 0;
    #pragma unroll
    for (int j = 0; j < 4; ++j) {
        int idx = i0 + j;
        v[j] = (idx < N) ? cnt[idx] : 0;
        s += v[j];
    }
    sh[t] = s;
    __syncthreads();
    for (int st = 1; st < 256; st <<= 1) {
        int a = (t >= st) ? sh[t - st] : 0;
        __syncthreads();
        sh[t] += a;
        __syncthreads();
    }
    int run = sh[t] - s + part[b];
    #pragma unroll
    for (int j = 0; j < 4; ++j) {
        int idx = i0 + j;
        if (idx < N) offs[idx] = run;
        run += v[j];
    }
}

__global__ void place_k(const int* __restrict__ eidx, int* __restrict__ offs,
                        int* __restrict__ ssrc, int* __restrict__ sdst,
                        int* __restrict__ seid, int E, int N) {
    int e = blockIdx.x * blockDim.x + threadIdx.x;
    if (e >= E) return;
    int d = eidx[(size_t)E + e]; if ((unsigned)d >= (unsigned)N) d = 0;
    int s = eidx[e];             if ((unsigned)s >= (unsigned)N) s = 0;
    int p = atomicAdd(&offs[d], 1);
    ssrc[p] = s; sdst[p] = d; seid[p] = e;
}

// ---- edge kernel: MFMA f16-split, frag-major weights, seg-scan epilogue -----
__global__ __launch_bounds__(256)
void GraphMessagePassing_5952824672257_kernel(
    const f16* __restrict__ nh, const f16* __restrict__ nl,   // [N,64] hi/lo
    const float* __restrict__ edgef,                          // [E,16] f32
    const int* __restrict__ ssrc, const int* __restrict__ sdst,
    const int* __restrict__ seid,
    const f16* __restrict__ W1F, const f16* __restrict__ W2F, // frag-major
    const float* __restrict__ b1, const float* __restrict__ b2,
    float* __restrict__ agg, int n_edges, int n_nodes)
{
    __shared__ __align__(16) char smem[18432];
    f16*   Hhi = (f16*)smem;             // [64][72]
    f16*   Hlo = (f16*)(smem + 9216);    // [64][72]
    float* F   = (float*)smem;           // [64][68] aliases H after GEMM2

    const int lane = threadIdx.x & 63;
    const int wid  = threadIdx.x >> 6;
    const int r16  = lane & 15;
    const int g    = lane >> 4;
    const long base = (long)blockIdx.x * 64 + wid * 16;

    long es = base + r16;
    if (es >= n_edges) es = n_edges - 1;
    const int s   = ssrc[es];            // coalesced
    const int eid = seid[es];

    // dsts for the scan: one coalesced load, broadcast via shfl later
    long ds_i = base + r16;
    if (ds_i >= n_edges) ds_i = n_edges - 1;
    const int dv = sdst[ds_i];

    // ---- GEMM1: C1[16e][64ch] = X[16e][96k] @ W1[96k][64ch]
    f32x4 acc[4] = {{0.f,0.f,0.f,0.f},{0.f,0.f,0.f,0.f},
                    {0.f,0.f,0.f,0.f},{0.f,0.f,0.f,0.f}};
    #pragma unroll
    for (int kt = 0; kt < 2; ++kt) {
        const int k0 = kt * 32 + g * 8;
        f16x8 ahi = *(const f16x8*)&nh[(size_t)s * 64 + k0];
        f16x8 alo = *(const f16x8*)&nl[(size_t)s * 64 + k0];
        #pragma unroll
        for (int nt = 0; nt < 4; ++nt) {
            const int fo = (kt * 4 + nt) * 512 + lane * 8;     // coalesced 1KB
            f16x8 bhi = *(const f16x8*)&W1F[fo];
            f16x8 blo = *(const f16x8*)&W1F[6144 + fo];
            acc[nt] = MFMA16(ahi, bhi, acc[nt]);
            acc[nt] = MFMA16(ahi, blo, acc[nt]);
            acc[nt] = MFMA16(alo, bhi, acc[nt]);
        }
    }
    {   // k 64..95: g<2 from edgef (gathered via seid), g>=2 zero-pad
        f16x8 ahi = {}; f16x8 alo = {};
        if (g < 2) {
            const float* ep = edgef + (size_t)eid * 16 + g * 8;
            float4 v0 = *(const float4*)(ep);
            float4 v1 = *(const float4*)(ep + 4);
            float xv[8] = {v0.x, v0.y, v0.z, v0.w, v1.x, v1.y, v1.z, v1.w};
            #pragma unroll
            for (int j = 0; j < 8; ++j) {
                f16 h = (f16)xv[j];
                ahi[j] = h;
                alo[j] = (f16)(xv[j] - (float)h);
            }
        }
        #pragma unroll
        for (int nt = 0; nt < 4; ++nt) {
            const int fo = (2 * 4 + nt) * 512 + lane * 8;
            f16x8 bhi = *(const f16x8*)&W1F[fo];
            f16x8 blo = *(const f16x8*)&W1F[6144 + fo];
            acc[nt] = MFMA16(ahi, bhi, acc[nt]);
            acc[nt] = MFMA16(ahi, blo, acc[nt]);
            acc[nt] = MFMA16(alo, bhi, acc[nt]);
        }
    }

    // ---- +b1, relu, f16-split -> H tile (wave-private rows)
    const int ebase = wid * 16 + g * 4;
    #pragma unroll
    for (int nt = 0; nt < 4; ++nt) {
        const int ch = nt * 16 + r16;
        const float bv = b1[ch];
        #pragma unroll
        for (int reg = 0; reg < 4; ++reg) {
            float h = fmaxf(acc[nt][reg] + bv, 0.f);
            f16 hh = (f16)h;
            Hhi[(ebase + reg) * 72 + ch] = hh;
            Hlo[(ebase + reg) * 72 + ch] = (f16)(h - (float)hh);
        }
    }
    __syncthreads();

    // ---- GEMM2: C2[16e][64ch] = H[16e][64k] @ W2[64k][64ch]
    f32x4 acc2[4] = {{0.f,0.f,0.f,0.f},{0.f,0.f,0.f,0.f},
                     {0.f,0.f,0.f,0.f},{0.f,0.f,0.f,0.f}};
    const int arow = wid * 16 + r16;
    #pragma unroll
    for (int kt = 0; kt < 2; ++kt) {
        const int k0 = kt * 32 + g * 8;
        f16x8 ahi = *(const f16x8*)&Hhi[arow * 72 + k0];
        f16x8 alo = *(const f16x8*)&Hlo[arow * 72 + k0];
        #pragma unroll
        for (int nt = 0; nt < 4; ++nt) {
            const int fo = (kt * 4 + nt) * 512 + lane * 8;
            f16x8 bhi = *(const f16x8*)&W2F[fo];
            f16x8 blo = *(const f16x8*)&W2F[4096 + fo];
            acc2[nt] = MFMA16(ahi, bhi, acc2[nt]);
            acc2[nt] = MFMA16(ahi, blo, acc2[nt]);
            acc2[nt] = MFMA16(alo, bhi, acc2[nt]);
        }
    }
    __syncthreads();   // all H reads done before F aliases the same bytes

    // ---- messages(+b2) -> F[edge][ch]
    #pragma unroll
    for (int nt = 0; nt < 4; ++nt) {
        const int ch = nt * 16 + r16;
        const float bv = b2[ch];
        #pragma unroll
        for (int reg = 0; reg < 4; ++reg)
            F[(ebase + reg) * 68 + ch] = acc2[nt][reg] + bv;
    }

    // ---- segmented scan over 16 sorted edges; lane = channel; dsts via shfl
    const int c = lane;
    int curd = __shfl(dv, 0, 64);
    float accv = 0.f;
    #pragma unroll 1
    for (int i = 0; i < 16; ++i) {
        const bool v = (base + i) < n_edges;
        const int dnew = v ? __shfl(dv, i, 64) : curd;   // wave-uniform value
        if (dnew != curd) {
            atomicAdd(agg + (size_t)curd * 64 + c, accv);
            accv = 0.f; curd = dnew;
        }
        if (v) accv += F[(wid * 16 + i) * 68 + c];
    }
    atomicAdd(agg + (size_t)curd * 64 + c, accv);
}

// ---- node kernel: same MFMA structure, no gathers, plain stores -------------
__global__ __launch_bounds__(256)
void node_mlp_mfma(
    const f16* __restrict__ nh, const f16* __restrict__ nl,   // [N,64] hi/lo
    const float* __restrict__ agg,                            // [N,64] f32
    const f16* __restrict__ U1F, const f16* __restrict__ U2F, // frag-major
    const float* __restrict__ b1, const float* __restrict__ b2,
    float* __restrict__ out, int n_nodes)
{
    __shared__ __align__(16) f16 Hhi[64 * 72];
    __shared__ __align__(16) f16 Hlo[64 * 72];

    const int lane = threadIdx.x & 63;
    const int wid  = threadIdx.x >> 6;
    const int r16  = lane & 15;
    const int g    = lane >> 4;
    const long base = (long)blockIdx.x * 64 + wid * 16;

    long row = base + r16;
    if (row >= n_nodes) row = n_nodes - 1;

    // ---- GEMM1: C1[16n][64ch] = [node|agg][16n][128k] @ U1[128k][64ch]
    f32x4 acc[4] = {{0.f,0.f,0.f,0.f},{0.f,0.f,0.f,0.f},
                    {0.f,0.f,0.f,0.f},{0.f,0.f,0.f,0.f}};
    #pragma unroll
    for (int kt = 0; kt < 4; ++kt) {
        f16x8 ahi, alo;
        if (kt < 2) {            // k 0..63 from pre-split node planes
            const int k0 = kt * 32 + g * 8;
            ahi = *(const f16x8*)&nh[(size_t)row * 64 + k0];
            alo = *(const f16x8*)&nl[(size_t)row * 64 + k0];
        } else {                 // k 64..127 from agg (split in-register)
            const int k0 = (kt - 2) * 32 + g * 8;
            const float* ap = agg + (size_t)row * 64 + k0;
            float4 v0 = *(const float4*)(ap);
            float4 v1 = *(const float4*)(ap + 4);
            float xv[8] = {v0.x, v0.y, v0.z, v0.w, v1.x, v1.y, v1.z, v1.w};
            #pragma unroll
            for (int j = 0; j < 8; ++j) {
                f16 h = (f16)xv[j];
                ahi[j] = h;
                alo[j] = (f16)(xv[j] - (float)h);
            }
        }
        #pragma unroll
        for (int nt = 0; nt < 4; ++nt) {
            const int fo = (kt * 4 + nt) * 512 + lane * 8;
            f16x8 bhi = *(const f16x8*)&U1F[fo];
            f16x8 blo = *(const f16x8*)&U1F[8192 + fo];
            acc[nt] = MFMA16(ahi, bhi, acc[nt]);
            acc[nt] = MFMA16(ahi, blo, acc[nt]);
            acc[nt] = MFMA16(alo, bhi, acc[nt]);
        }
    }

    // ---- +b1, relu, split -> H tile
    const int ebase = wid * 16 + g * 4;
    #pragma unroll
    for (int nt = 0; nt < 4; ++nt) {
        const int ch = nt * 16 + r16;
        const float bv = b1[ch];
        #pragma unroll
        for (int reg = 0; reg < 4; ++reg) {
            float h = fmaxf(acc[nt][reg] + bv, 0.f);
            f16 hh = (f16)h;
            Hhi[(ebase + reg) * 72 + ch] = hh;
            Hlo[(ebase + reg) * 72 + ch] = (f16)(h - (float)hh);
        }
    }
    __syncthreads();

    // ---- GEMM2
    f32x4 acc2[4] = {{0.f,0.f,0.f,0.f},{0.f,0.f,0.f,0.f},
                     {0.f,0.f,0.f,0.f},{0.f,0.f,0.f,0.f}};
    const int arow = wid * 16 + r16;
    #pragma unroll
    for (int kt = 0; kt < 2; ++kt) {
        const int k0 = kt * 32 + g * 8;
        f16x8 ahi = *(const f16x8*)&Hhi[arow * 72 + k0];
        f16x8 alo = *(const f16x8*)&Hlo[arow * 72 + k0];
        #pragma unroll
        for (int nt = 0; nt < 4; ++nt) {
            const int fo = (kt * 4 + nt) * 512 + lane * 8;
            f16x8 bhi = *(const f16x8*)&U2F[fo];
            f16x8 blo = *(const f16x8*)&U2F[4096 + fo];
            acc2[nt] = MFMA16(ahi, bhi, acc2[nt]);
            acc2[nt] = MFMA16(ahi, blo, acc2[nt]);
            acc2[nt] = MFMA16(alo, bhi, acc2[nt]);
        }
    }

    // ---- +b2, direct stores (4 x 64B segments per instr)
    #pragma unroll
    for (int nt = 0; nt < 4; ++nt) {
        const int ch = nt * 16 + r16;
        const float bv = b2[ch];
        #pragma unroll
        for (int reg = 0; reg < 4; ++reg) {
            const long orow = base + g * 4 + reg;
            if (orow < n_nodes)
                out[(size_t)orow * 64 + ch] = acc2[nt][reg] + bv;
        }
    }
}

extern "C" void kernel_launch(void* const* d_in, const int* in_sizes, int n_in,
                              void* d_out, int out_size, void* d_ws, size_t ws_size,
                              hipStream_t stream) {
    const float* nodef = (const float*)d_in[0];
    const float* edgef = (const float*)d_in[1];
    const int*   eidx  = (const int*)d_in[2];
    const float* w_m1  = (const float*)d_in[3];
    const float* b_m1  = (const float*)d_in[4];
    const float* w_m2  = (const float*)d_in[5];
    const float* b_m2  = (const float*)d_in[6];
    const float* w_u1  = (const float*)d_in[7];
    const float* b_u1  = (const float*)d_in[8];
    const float* w_u2  = (const float*)d_in[9];
    const float* b_u2  = (const float*)d_in[10];
    float* out = (float*)d_out;

    const int n_nodes = out_size / 64;
    const int n_edges = in_sizes[2] / 2;
    if (n_edges <= 0 || n_nodes <= 0) return;

    // workspace layout
    char* wsb = (char*)d_ws;
    size_t o = 0;
    float* agg = (float*)wsb;     o += ((size_t)n_nodes * 64 * 4 + 255) & ~(size_t)255;
    f16* nh  = (f16*)(wsb + o);   o += (size_t)n_nodes * 64 * 2;
    f16* nl  = (f16*)(wsb + o);   o += (size_t)n_nodes * 64 * 2;
    f16* W1F = (f16*)(wsb + o);   o += 12288 * 2;
    f16* W2F = (f16*)(wsb + o);   o += 8192 * 2;
    f16* U1F = (f16*)(wsb + o);   o += 16384 * 2;
    f16* U2F = (f16*)(wsb + o);   o += 8192 * 2;
    o = (o + 255) & ~(size_t)255;
    int* cnt  = (int*)(wsb + o);  o += (size_t)n_nodes * 4;
    int* offs = (int*)(wsb + o);  o += (size_t)n_nodes * 4;
    int* part = (int*)(wsb + o);  o += 4096;
    int* ssrc = (int*)(wsb + o);  o += (size_t)n_edges * 4;
    int* sdst = (int*)(wsb + o);  o += (size_t)n_edges * 4;
    int* seid = (int*)(wsb + o);  o += (size_t)n_edges * 4;

    fprintf(stderr, "[KL] fragmajor+sorted E=%d N=%d ws=%zu used=%zu\n",
            n_edges, n_nodes, ws_size, o);
    fflush(stderr);

    hipMemsetAsync(agg, 0, (size_t)n_nodes * 64 * sizeof(float), stream);
    hipMemsetAsync(cnt, 0, (size_t)n_nodes * sizeof(int), stream);

    // conversions
    const int n4 = n_nodes * 64 / 4;
    conv_features<<<(n4 + 255) / 256, 256, 0, stream>>>(nodef, nh, nl, n4);
    conv_wfrag<<<(22528 + 255) / 256, 256, 0, stream>>>(
        w_m1, w_m2, w_u1, w_u2, W1F, W2F, U1F, U2F);

    // dst counting-sort
    const int nb = (n_nodes + 1023) / 1024;
    hist_k<<<1024, 256, 0, stream>>>(eidx + n_edges, cnt, n_edges, n_nodes);
    scan_part<<<nb, 256, 0, stream>>>(cnt, part, n_nodes);
    scan_top<<<1, 64, 0, stream>>>(part, nb);
    scan_fin<<<nb, 256, 0, stream>>>(cnt, part, offs, n_nodes);
    place_k<<<(n_edges + 255) / 256, 256, 0, stream>>>(
        eidx, offs, ssrc, sdst, seid, n_edges, n_nodes);

    // edge phase
    const int blocks_e = (n_edges + 63) / 64;
    GraphMessagePassing_5952824672257_kernel<<<blocks_e, 256, 0, stream>>>(
        nh, nl, edgef, ssrc, sdst, seid, W1F, W2F,
        b_m1, b_m2, agg, n_edges, n_nodes);

    // node phase
    const int blocks_n = (n_nodes + 63) / 64;
    node_mlp_mfma<<<blocks_n, 256, 0, stream>>>(
        nh, nl, agg, U1F, U2F, b_u1, b_u2, out, n_nodes);

    hipError_t le = hipGetLastError();
    fprintf(stderr, "[KL] last=%d(%s)\n", (int)le, hipGetErrorName(le));
    fflush(stderr);
}